// Round 16
// baseline (544.563 us; speedup 1.0000x reference)
//
#include <hip/hip_runtime.h>
#include <hip/hip_bf16.h>
#include <math.h>

// GATNet round 16: channel-chunked h1 layout kills agg1's 8-XCD refetch.
// r15 agg1: FETCH 229MB = 8 XCDs x full 25.6MB table (every wave reads the
// whole 512B row). Now h1 is stored as 8 chunk regions h1c[c8][n][64]
// (64B = all 8 heads' octet c8). agg1 waves are (node, c8) with c8 = block
// lid&7 -> XCD affinity: each XCD only touches its 3.2MB slice. Lane =
// (edge-slot, head): one coalesced 64B line per edge, softmax + head-mean
// in-wave (xor reductions). gemm1 epilogue stores chunked (8B pieces from
// LDS repack; same-XCD head-blocks merge lines in L2). Layer 2 untouched.

#define NEG_SLOPE 0.2f

typedef short v8s __attribute__((ext_vector_type(8)));
typedef float v4f __attribute__((ext_vector_type(4)));
typedef float v2f __attribute__((ext_vector_type(2)));
typedef unsigned short u16;
typedef unsigned int u32;
typedef unsigned char u8;

__device__ __forceinline__ u16 f2bf(float f) {
    union { float f; u32 u; } v; v.f = f;
    u32 r = v.u + 0x7fffu + ((v.u >> 16) & 1u);
    return (u16)(r >> 16);
}
__device__ __forceinline__ float lrelu_exp(float e) {
    e = (e > 0.f) ? e : NEG_SLOPE * e;
    return __expf(e);
}
__device__ __forceinline__ void dec8(uint2 r, float* h) {
    v2f a = __builtin_amdgcn_cvt_pk_f32_fp8(r.x, false);
    v2f b = __builtin_amdgcn_cvt_pk_f32_fp8(r.x, true);
    v2f c = __builtin_amdgcn_cvt_pk_f32_fp8(r.y, false);
    v2f d = __builtin_amdgcn_cvt_pk_f32_fp8(r.y, true);
    h[0] = a.x; h[1] = a.y; h[2] = b.x; h[3] = b.y;
    h[4] = c.x; h[5] = c.y; h[6] = d.x; h[7] = d.y;
}
__device__ __forceinline__ u8 enc8(float v) {
    u32 p = __builtin_amdgcn_cvt_pk_fp8_f32(v, v, 0u, false);
    return (u8)(p & 0xffu);
}

// ---------------- fused histogram + fp32->bf16 casts ----------------

__global__ __launch_bounds__(256) void histcast_k(const int* __restrict__ ei, int* __restrict__ deg,
                                                  int E, int Nn, int NBh,
                                                  const float* __restrict__ x, u16* __restrict__ xb,
                                                  const float* __restrict__ W0, u16* __restrict__ W0b,
                                                  const float* __restrict__ W2, u16* __restrict__ W2b,
                                                  int nx, int n0c, int n2c) {
    int b = blockIdx.x;
    if (b < NBh) {
        int e = b * 256 + threadIdx.x;
        int ET = E + Nn;
        if (e >= ET) return;
        int d = (e < E) ? ei[E + e] : (e - E);
        atomicAdd(&deg[d], 1);
    } else {
        int i = ((b - NBh) * 256 + threadIdx.x) * 4;
        const float* in; u16* out;
        if (i < nx)            { in = x;  out = xb; }
        else if (i < nx + n0c) { in = W0; out = W0b; i -= nx; }
        else if (i < nx + n0c + n2c) { in = W2; out = W2b; i -= nx + n0c; }
        else return;
        float4 v = *reinterpret_cast<const float4*>(in + i);
        ushort4 o;
        o.x = f2bf(v.x); o.y = f2bf(v.y); o.z = f2bf(v.z); o.w = f2bf(v.w);
        *reinterpret_cast<ushort4*>(out + i) = o;
    }
}

// ---------------- scanA: per-1024-chunk inclusive scan + degree histogram ----------------

__global__ __launch_bounds__(1024) void scanA_k(const int* __restrict__ deg, int* __restrict__ incl,
                                                int* __restrict__ bsum, int* __restrict__ dbin, int n) {
    __shared__ int wsum[16];
    __shared__ int dh[256];
    int t = threadIdx.x;
    if (t < 256) dh[t] = 0;
    int i = blockIdx.x * 1024 + t;
    int v = (i < n) ? deg[i] : 0;
    __syncthreads();
    if (i < n) atomicAdd(&dh[v < 255 ? v : 255], 1);
    int lane = t & 63, wid = t >> 6;
    int sv = v;
    for (int off = 1; off < 64; off <<= 1) {
        int u = __shfl_up(sv, off, 64);
        if (lane >= off) sv += u;
    }
    if (lane == 63) wsum[wid] = sv;
    __syncthreads();
    if (t < 16) {
        int w = wsum[t];
        for (int off = 1; off < 16; off <<= 1) {
            int u = __shfl_up(w, off, 64);
            if (t >= off) w += u;
        }
        wsum[t] = w;
    }
    if (t < 256 && dh[t] > 0) atomicAdd(&dbin[t], dh[t]);
    __syncthreads();
    int pre = (wid > 0) ? wsum[wid - 1] : 0;
    int inc = pre + sv;
    if (i < n) incl[i] = inc;
    if (t == 1023) bsum[blockIdx.x] = inc;
}

// ---------------- scanBC: rowstart ----------------

__global__ __launch_bounds__(256) void scanBC_k(const int* __restrict__ incl, const int* __restrict__ deg,
                                                const int* __restrict__ bsum, int* __restrict__ rowstart,
                                                int n, int B) {
    __shared__ int sb[65];
    int t = threadIdx.x;
    if (t < 64) {
        int v = (t < B) ? bsum[t] : 0;
        int sv = v;
        for (int off = 1; off < 64; off <<= 1) {
            int u = __shfl_up(sv, off, 64);
            if (t >= off) sv += u;
        }
        sb[t] = sv - v;
        if (t == 63) sb[64] = sv;
    }
    __syncthreads();
    int i = blockIdx.x * 256 + t;
    if (i < n) rowstart[i] = sb[i >> 10] + incl[i] - deg[i];
    if (i == 0) rowstart[n] = sb[64];
}

// ---------------- scatter: edges -> CSR srcs; node degree-sort (block-aggregated, DESC) ----------------

__global__ __launch_bounds__(256) void scatter_k(const int* __restrict__ ei,
                                                 const int* __restrict__ rowstart,
                                                 int* __restrict__ cursor,
                                                 int* __restrict__ srcs, int E, int Nn,
                                                 const int* __restrict__ deg,
                                                 const int* __restrict__ dbin,
                                                 int* __restrict__ dcur,
                                                 int* __restrict__ order) {
    int b = blockIdx.x, t = threadIdx.x;
    int e = b * 256 + t;
    int ET = E + Nn;
    if (e < ET) {
        int s, d;
        if (e < E) { s = ei[e]; d = ei[E + e]; }
        else       { s = e - E; d = e - E; }
        int pos = atomicAdd(&cursor[d], 1);
        srcs[rowstart[d] + pos] = s;
    }
    if (b * 256 < Nn) {
        __shared__ int ws4[4];
        __shared__ int sbase[256];
        __shared__ int lhist[256];
        __shared__ int lbase[256];
        lhist[t] = 0;
        int v = dbin[t];
        int lane = t & 63, wid = t >> 6;
        int sv = v;
        for (int off = 1; off < 64; off <<= 1) {
            int u = __shfl_up(sv, off, 64);
            if (lane >= off) sv += u;
        }
        if (lane == 63) ws4[wid] = sv;
        __syncthreads();
        int add = 0;
        for (int k = 0; k < wid; k++) add += ws4[k];
        sbase[t] = add + sv - v;
        __syncthreads();
        int i = b * 256 + t;
        int d = 0, rank = -1;
        if (i < Nn) {
            d = deg[i]; d = (d < 255) ? d : 255;
            rank = atomicAdd(&lhist[d], 1);
        }
        __syncthreads();
        int cnt = lhist[t];
        if (cnt > 0) lbase[t] = atomicAdd(&dcur[t], cnt);
        __syncthreads();
        if (i < Nn) order[Nn - 1 - (sbase[d] + lbase[d] + rank)] = i;
    }
}

// ---------------- bf16 MFMA GEMM -> fp8 C ----------------
// 128x64 tile, 4 waves, B slab staged once, A streamed w/ 4-deep pipeline,
// XCD swizzle (col-blocks of a row-slab share lid%8).
// Layer1 (do_att): C stored CHUNKED h1c[c8][n][h*8+j] (8B pieces) + fused logits.
// Layer2: standard row-major C with 16B stores.

template<int KK>
__global__ __launch_bounds__(256, 4) void gemm_mfma(const u16* __restrict__ Ab,
                                                    const u16* __restrict__ Bb,
                                                    u8* __restrict__ Cf, int M, int Nc,
                                                    const float* __restrict__ avs_vec,
                                                    const float* __restrict__ avd_vec,
                                                    float* as_out, float* ad_out) {
    constexpr int SB = KK + 8;
    constexpr int BBY = 64 * SB * 2;
    constexpr int LBY = (BBY > 10240) ? BBY : 10240;
    __shared__ __align__(16) u8 lds[LBY];
    u16* Bs = reinterpret_cast<u16*>(lds);
    const int t = threadIdx.x;

    const int lid = blockIdx.y * gridDim.x + blockIdx.x;
    const int GY = gridDim.y;
    const int r8 = lid & 7;
    const int rest = lid >> 3;
    const int row_blk = (rest / GY) * 8 + r8;
    const int col_blk = rest % GY;
    const int m0 = row_blk * 128;
    const int n0 = col_blk * 64;
    if (m0 >= M) return;

    const int w = t >> 6, lane = t & 63;
    const int wr = w * 32;
    const int q = lane >> 4, l16 = lane & 15;

    constexpr int NKC = KK / 32;
    constexpr int PF = (NKC < 4) ? NKC : 4;

    const u16* A0 = Ab + (size_t)(m0 + wr + l16) * KK + q * 8;
    const u16* A1 = A0 + (size_t)16 * KK;
    v8s pa0[PF], pa1[PF];
#pragma unroll
    for (int k = 0; k < PF; k++) {
        pa0[k] = *reinterpret_cast<const v8s*>(A0 + k * 32);
        pa1[k] = *reinterpret_cast<const v8s*>(A1 + k * 32);
    }

    constexpr int CH = KK / 8;
#pragma unroll
    for (int c = t; c < 64 * CH; c += 256) {
        int row = c / CH, ch = c % CH;
        int gn = n0 + row;
        uint4 vb = make_uint4(0u, 0u, 0u, 0u);
        if (gn < Nc) vb = *reinterpret_cast<const uint4*>(Bb + (size_t)gn * KK + ch * 8);
        *reinterpret_cast<uint4*>(&Bs[row * SB + ch * 8]) = vb;
    }
    __syncthreads();

    v4f acc[2][4];
#pragma unroll
    for (int i = 0; i < 2; i++)
#pragma unroll
        for (int j = 0; j < 4; j++) acc[i][j] = (v4f){0.f, 0.f, 0.f, 0.f};

#pragma unroll
    for (int kc = 0; kc < NKC; kc++) {
        v8s a0 = pa0[kc % PF];
        v8s a1 = pa1[kc % PF];
        if (kc + PF < NKC) {
            pa0[kc % PF] = *reinterpret_cast<const v8s*>(A0 + (kc + PF) * 32);
            pa1[kc % PF] = *reinterpret_cast<const v8s*>(A1 + (kc + PF) * 32);
        }
        v8s bf[4];
#pragma unroll
        for (int j = 0; j < 4; j++)
            bf[j] = *reinterpret_cast<const v8s*>(&Bs[(j * 16 + l16) * SB + kc * 32 + q * 8]);
#pragma unroll
        for (int j = 0; j < 4; j++) {
            acc[0][j] = __builtin_amdgcn_mfma_f32_16x16x32_bf16(a0, bf[j], acc[0][j], 0, 0, 0);
            acc[1][j] = __builtin_amdgcn_mfma_f32_16x16x32_bf16(a1, bf[j], acc[1][j], 0, 0, 0);
        }
    }

    const bool do_att = (as_out != nullptr);
    float avs[4], avd[4];
    if (do_att) {
#pragma unroll
        for (int j = 0; j < 4; j++) {
            avs[j] = avs_vec[n0 + j * 16 + l16];
            avd[j] = avd_vec[n0 + j * 16 + l16];
        }
    }
    const int head = n0 >> 6;

    __syncthreads();   // B reads done; reuse lds for C repack
    u8* Cs = lds;
#pragma unroll
    for (int i = 0; i < 2; i++) {
#pragma unroll
        for (int r = 0; r < 4; r++) {
            int row = wr + i * 16 + q * 4 + r;
#pragma unroll
            for (int j = 0; j < 4; j++)
                Cs[row * 80 + j * 16 + l16] = enc8(acc[i][j][r]);
            if (do_att) {
                int gm = m0 + row;
                float ps = 0.f, pd = 0.f;
#pragma unroll
                for (int j = 0; j < 4; j++) {
                    float v = acc[i][j][r];
                    ps = fmaf(v, avs[j], ps);
                    pd = fmaf(v, avd[j], pd);
                }
#pragma unroll
                for (int m = 1; m < 16; m <<= 1) {
                    ps += __shfl_xor(ps, m, 64);
                    pd += __shfl_xor(pd, m, 64);
                }
                if (l16 == 0 && gm < M) {
                    as_out[gm * 8 + head] = ps;
                    ad_out[gm * 8 + head] = pd;
                }
            }
        }
    }
    __syncthreads();
    if (do_att) {
        // chunked store: h1c[c8][n][head*8..head*8+8) , 8B per (row,c8)
#pragma unroll
        for (int it = 0; it < 4; it++) {
            int idx = it * 256 + t;
            int row = idx >> 3, c8 = idx & 7;
            int gm = m0 + row;
            if (gm < M)
                *reinterpret_cast<uint2*>(Cf + (size_t)c8 * M * 64 + (size_t)gm * 64 + head * 8) =
                    *reinterpret_cast<const uint2*>(&Cs[row * 80 + c8 * 8]);
        }
    } else {
#pragma unroll
        for (int it = 0; it < 2; it++) {
            int idx = it * 256 + t;
            int row = idx >> 2, ch = idx & 3;
            int gm = m0 + row;
            if (gm < M)
                *reinterpret_cast<uint4*>(Cf + (size_t)gm * Nc + n0 + ch * 16) =
                    *reinterpret_cast<const uint4*>(&Cs[row * 80 + ch * 16]);
        }
    }
}

// ---------------- layer-1 aggregation: wave = (node, c8); lane = (edge-slot, head) ----------------
// h1c chunked: one coalesced 64B line per edge. c8 = block lid&7 -> XCD affinity.

__global__ __launch_bounds__(256) void agg1_k(const u8* __restrict__ h1c,
                                              const float* __restrict__ as1, const float* __restrict__ ad1,
                                              const int* __restrict__ srcs, const int* __restrict__ rowstart,
                                              const int* __restrict__ order,
                                              const float* __restrict__ b0, u16* __restrict__ x1b, int Nn) {
    int wave = threadIdx.x >> 6, lane = threadIdx.x & 63;
    int lid = blockIdx.x;
    int c8 = lid & 7, nc = lid >> 3;
    int gid = nc * 4 + wave;
    if (gid >= Nn) return;
    int n = __builtin_amdgcn_readfirstlane(order[gid]);
    const int eg = lane >> 3;     // edge slot 0..7
    const int h  = lane & 7;      // head 0..7
    const float adl = ad1[n * 8 + h];
    const u8* base = h1c + (size_t)c8 * Nn * 64;
    float acc[8] = {0, 0, 0, 0, 0, 0, 0, 0};
    float dsum = 0.f;
    int beg = rowstart[n], end = rowstart[n + 1];
    int sfb = srcs[beg];          // safe fallback for inactive slots
    for (int i0 = beg; i0 < end; i0 += 8) {
        int i = i0 + eg;
        bool act = (i < end);
        int s = act ? srcs[i] : sfb;
        uint2 raw = *reinterpret_cast<const uint2*>(base + (u32)s * 64u + h * 8u);
        float e = as1[s * 8 + h] + adl;
        float p = act ? lrelu_exp(e) : 0.f;
        dsum += p;
        float hv[8];
        dec8(raw, hv);
#pragma unroll
        for (int j = 0; j < 8; j++) acc[j] = fmaf(p, hv[j], acc[j]);
    }
    // reduce over edge slots (lane bits 3..5)
#pragma unroll
    for (int j = 0; j < 8; j++) {
        acc[j] += __shfl_xor(acc[j], 8, 64);
        acc[j] += __shfl_xor(acc[j], 16, 64);
        acc[j] += __shfl_xor(acc[j], 32, 64);
    }
    dsum += __shfl_xor(dsum, 8, 64);
    dsum += __shfl_xor(dsum, 16, 64);
    dsum += __shfl_xor(dsum, 32, 64);
    float inv = 1.f / (dsum + 1e-16f);
    float r[8];
#pragma unroll
    for (int j = 0; j < 8; j++) r[j] = acc[j] * inv;
    // mean over heads (lane bits 0..2)
#pragma unroll
    for (int j = 0; j < 8; j++) {
        r[j] += __shfl_xor(r[j], 1, 64);
        r[j] += __shfl_xor(r[j], 2, 64);
        r[j] += __shfl_xor(r[j], 4, 64);
    }
    if (lane == 0) {
        u16 o[8];
#pragma unroll
        for (int j = 0; j < 8; j++) {
            float v = r[j] * 0.125f + b0[c8 * 8 + j];
            o[j] = f2bf((v > 0.f) ? v : 0.f);
        }
        *reinterpret_cast<uint4*>(x1b + (size_t)n * 64 + c8 * 8) =
            *reinterpret_cast<const uint4*>(o);
    }
}

// ---------------- layer-2 attention logits ----------------

__global__ __launch_bounds__(256) void att2_k(const u8* __restrict__ h2f,
                                              const float* __restrict__ a2s, const float* __restrict__ a2d,
                                              float* __restrict__ as2, float* __restrict__ ad2, int Nn) {
    int t = blockIdx.x * 256 + threadIdx.x;
    if (t >= Nn * 8) return;
    int n = t >> 3, h = t & 7;
    const u8* hr = h2f + (size_t)n * 320 + h * 40;
    float s1 = 0.f, s2 = 0.f;
#pragma unroll
    for (int b = 0; b < 5; b++) {
        uint2 raw = *reinterpret_cast<const uint2*>(hr + b * 8);
        float h8[8];
        dec8(raw, h8);
#pragma unroll
        for (int j = 0; j < 8; j++) {
            int c = h * 40 + b * 8 + j;
            s1 = fmaf(h8[j], a2s[c], s1);
            s2 = fmaf(h8[j], a2d[c], s2);
        }
    }
    as2[t] = s1;
    ad2[t] = s2;
}

// ---------------- layer-2 aggregation (degree-sorted) + head-mean + log_softmax ----------------

__global__ __launch_bounds__(256) void agg2_k(const u8* __restrict__ h2f,
                                              const float* __restrict__ as2, const float* __restrict__ ad2,
                                              const int* __restrict__ srcs, const int* __restrict__ rowstart,
                                              const int* __restrict__ order,
                                              const float* __restrict__ b2, float* __restrict__ out, int Nn) {
    __shared__ float smem[4][320];
    int wave = threadIdx.x >> 6, lane = threadIdx.x & 63;
    int gid = blockIdx.x * 4 + wave;
    bool active = (gid < Nn);
    int n = 0;
    if (active) n = __builtin_amdgcn_readfirstlane(order[gid]);
    bool ld = active && (lane < 40);
    const int hl = lane / 5;
    float adl = ld ? ad2[n * 8 + hl] : 0.f;
    float acc[8] = {0, 0, 0, 0, 0, 0, 0, 0};
    float dsum = 0.f;
    if (ld) {
        const u32 loff = (u32)lane * 8u;
        int beg = rowstart[n], end = rowstart[n + 1];
        int i = beg;
        for (; i + 8 <= end; i += 8) {
            int s[8];
#pragma unroll
            for (int u = 0; u < 8; u++) s[u] = __builtin_amdgcn_readfirstlane(srcs[i + u]);
            uint2 rw[8];
#pragma unroll
            for (int u = 0; u < 8; u++) rw[u] = *reinterpret_cast<const uint2*>(h2f + ((u32)s[u] * 320u + loff));
            float eg[8];
#pragma unroll
            for (int u = 0; u < 8; u++) eg[u] = as2[(u32)s[u] * 8u + hl];
            float p[8];
#pragma unroll
            for (int u = 0; u < 8; u++) { p[u] = lrelu_exp(eg[u] + adl); dsum += p[u]; }
#pragma unroll
            for (int u = 0; u < 8; u++) {
                float hv[8];
                dec8(rw[u], hv);
#pragma unroll
                for (int j = 0; j < 8; j++) acc[j] = fmaf(p[u], hv[j], acc[j]);
            }
        }
        for (; i + 4 <= end; i += 4) {
            int s[4];
#pragma unroll
            for (int u = 0; u < 4; u++) s[u] = __builtin_amdgcn_readfirstlane(srcs[i + u]);
            uint2 rw[4];
#pragma unroll
            for (int u = 0; u < 4; u++) rw[u] = *reinterpret_cast<const uint2*>(h2f + ((u32)s[u] * 320u + loff));
            float eg[4];
#pragma unroll
            for (int u = 0; u < 4; u++) eg[u] = as2[(u32)s[u] * 8u + hl];
#pragma unroll
            for (int u = 0; u < 4; u++) {
                float p = lrelu_exp(eg[u] + adl);
                dsum += p;
                float hv[8];
                dec8(rw[u], hv);
#pragma unroll
                for (int j = 0; j < 8; j++) acc[j] = fmaf(p, hv[j], acc[j]);
            }
        }
        for (; i < end; i++) {
            int s = __builtin_amdgcn_readfirstlane(srcs[i]);
            uint2 raw = *reinterpret_cast<const uint2*>(h2f + ((u32)s * 320u + loff));
            float p = lrelu_exp(as2[(u32)s * 8u + hl] + adl);
            dsum += p;
            float hv[8];
            dec8(raw, hv);
#pragma unroll
            for (int j = 0; j < 8; j++) acc[j] = fmaf(p, hv[j], acc[j]);
        }
        float inv = 1.f / (dsum + 1e-16f);
#pragma unroll
        for (int j = 0; j < 8; j++) smem[wave][lane * 8 + j] = acc[j] * inv;
    }
    __syncthreads();
    if (active) {
        float v;
        if (lane < 40) {
            float ssum = 0.f;
#pragma unroll
            for (int h = 0; h < 8; h++) ssum += smem[wave][h * 40 + lane];
            v = ssum * 0.125f + b2[lane];
        } else {
            v = -INFINITY;
        }
        float m = v;
        for (int off = 32; off > 0; off >>= 1) m = fmaxf(m, __shfl_xor(m, off, 64));
        float ex = (lane < 40) ? __expf(v - m) : 0.f;
        float se = ex;
        for (int off = 32; off > 0; off >>= 1) se += __shfl_xor(se, off, 64);
        if (lane < 40) out[(size_t)n * 40 + lane] = v - m - __logf(se);
    }
}

// ---------------- launch ----------------

extern "C" void kernel_launch(void* const* d_in, const int* in_sizes, int n_in,
                              void* d_out, int out_size, void* d_ws, size_t ws_size,
                              hipStream_t stream) {
    const float* x   = (const float*)d_in[0];
    const int*   ei  = (const int*)d_in[1];
    const float* W0  = (const float*)d_in[3];
    const float* a0s = (const float*)d_in[4];
    const float* a0d = (const float*)d_in[5];
    const float* b0  = (const float*)d_in[6];
    const float* W2  = (const float*)d_in[7];
    const float* a2s = (const float*)d_in[8];
    const float* a2d = (const float*)d_in[9];
    const float* b2  = (const float*)d_in[10];
    float* out = (float*)d_out;

    const int Nn = in_sizes[0] / 256;   // 50000
    const int E  = in_sizes[1] / 2;     // 800000
    const int ET = E + Nn;
    const int NB = (Nn + 1023) / 1024;

    size_t off = 0;
    auto carve = [&](size_t bytes) -> void* {
        void* p = (char*)d_ws + off;
        off += (bytes + 255) & ~(size_t)255;
        return p;
    };
    u16*   xb       = (u16*)carve((size_t)Nn * 256 * 2);
    u16*   W0b      = (u16*)carve((size_t)512 * 256 * 2);
    u16*   W2b      = (u16*)carve((size_t)320 * 64 * 2);
    u8*    h1c      = (u8*)carve((size_t)Nn * 512);   // chunked: [c8][n][64]
    u16*   x1b      = (u16*)carve((size_t)Nn * 64 * 2);
    u8*    h2f      = (u8*)carve((size_t)Nn * 320);
    float* as1      = (float*)carve((size_t)Nn * 8 * 4);
    float* ad1      = (float*)carve((size_t)Nn * 8 * 4);
    float* as2      = (float*)carve((size_t)Nn * 8 * 4);
    float* ad2      = (float*)carve((size_t)Nn * 8 * 4);
    int*   deg      = (int*)carve((size_t)Nn * 4);
    int*   cursor   = (int*)carve((size_t)Nn * 4);
    int*   dbin     = (int*)carve(256 * 4);
    int*   dcur     = (int*)carve(256 * 4);
    int*   rowstart = (int*)carve((size_t)(Nn + 1) * 4);
    int*   srcs     = (int*)carve((size_t)ET * 4);
    int*   incl     = (int*)carve((size_t)Nn * 4);
    int*   bsum     = (int*)carve(64 * 4);
    int*   order    = (int*)carve((size_t)Nn * 4);

    const size_t zlen = (size_t)((char*)rowstart - (char*)deg);
    hipMemsetAsync(deg, 0, zlen, stream);

    const int nx = Nn * 256, n0c = 512 * 256, n2c = 320 * 64;
    const int NBh = (ET + 255) / 256;
    const int NBc = ((nx + n0c + n2c) / 4 + 255) / 256;
    histcast_k<<<NBh + NBc, 256, 0, stream>>>(ei, deg, E, Nn, NBh,
                                              x, xb, W0, W0b, W2, W2b, nx, n0c, n2c);
    scanA_k<<<NB, 1024, 0, stream>>>(deg, incl, bsum, dbin, Nn);
    scanBC_k<<<(Nn + 255) / 256, 256, 0, stream>>>(incl, deg, bsum, rowstart, Nn, NB);
    scatter_k<<<(ET + 255) / 256, 256, 0, stream>>>(ei, rowstart, cursor, srcs, E, Nn,
                                                    deg, dbin, dcur, order);

    const int GXr = (Nn + 127) / 128;
    const int GX  = ((GXr + 7) / 8) * 8;

    // layer 1: GEMM (chunked C) + fused logits
    gemm_mfma<256><<<dim3(GX, 8), 256, 0, stream>>>(
        xb, W0b, h1c, Nn, 512, a0s, a0d, as1, ad1);
    // agg1: grid = node-chunks x 8 channel-chunks (1-D; lid&7 = c8 = XCD)
    agg1_k<<<((Nn + 3) / 4) * 8, 256, 0, stream>>>(h1c, as1, ad1, srcs, rowstart, order, b0, x1b, Nn);

    // layer 2: GEMM (standard C), fp8 h2
    gemm_mfma<64><<<dim3(GX, 5), 256, 0, stream>>>(
        x1b, W2b, h2f, Nn, 320, nullptr, nullptr, nullptr, nullptr);
    att2_k<<<(Nn * 8 + 255) / 256, 256, 0, stream>>>(h2f, a2s, a2d, as2, ad2, Nn);
    agg2_k<<<(Nn + 3) / 4, 256, 0, stream>>>(h2f, as2, ad2, srcs, rowstart, order, b2, out, Nn);
}

// Round 17
// 377.275 us; speedup vs baseline: 1.4434x; 1.4434x over previous
//
#include <hip/hip_runtime.h>
#include <hip/hip_bf16.h>
#include <math.h>

// GATNet round 17: REVERT to round-15 (381us best). Round-16's channel-
// chunked h1 regressed 381->545us: softmax recomputed 8x (once per chunk
// wave), srcs/as1/order fill x8 across XCDs, FETCH rose 229->308MB.
// r15 config: B-slab-once + A-prefetch-pipeline + XCD-swizzled GEMM,
// degree-sorted aggs (block-aggregated counting sort), fp8 tables,
// fused layer-1 logits in GEMM epilogue.

#define NEG_SLOPE 0.2f

typedef short v8s __attribute__((ext_vector_type(8)));
typedef float v4f __attribute__((ext_vector_type(4)));
typedef float v2f __attribute__((ext_vector_type(2)));
typedef unsigned short u16;
typedef unsigned int u32;
typedef unsigned char u8;

__device__ __forceinline__ u16 f2bf(float f) {
    union { float f; u32 u; } v; v.f = f;
    u32 r = v.u + 0x7fffu + ((v.u >> 16) & 1u);
    return (u16)(r >> 16);
}
__device__ __forceinline__ float lrelu_exp(float e) {
    e = (e > 0.f) ? e : NEG_SLOPE * e;
    return __expf(e);
}
__device__ __forceinline__ void dec8(uint2 r, float* h) {
    v2f a = __builtin_amdgcn_cvt_pk_f32_fp8(r.x, false);
    v2f b = __builtin_amdgcn_cvt_pk_f32_fp8(r.x, true);
    v2f c = __builtin_amdgcn_cvt_pk_f32_fp8(r.y, false);
    v2f d = __builtin_amdgcn_cvt_pk_f32_fp8(r.y, true);
    h[0] = a.x; h[1] = a.y; h[2] = b.x; h[3] = b.y;
    h[4] = c.x; h[5] = c.y; h[6] = d.x; h[7] = d.y;
}
__device__ __forceinline__ u8 enc8(float v) {
    u32 p = __builtin_amdgcn_cvt_pk_fp8_f32(v, v, 0u, false);
    return (u8)(p & 0xffu);
}

// ---------------- fused histogram + fp32->bf16 casts ----------------

__global__ __launch_bounds__(256) void histcast_k(const int* __restrict__ ei, int* __restrict__ deg,
                                                  int E, int Nn, int NBh,
                                                  const float* __restrict__ x, u16* __restrict__ xb,
                                                  const float* __restrict__ W0, u16* __restrict__ W0b,
                                                  const float* __restrict__ W2, u16* __restrict__ W2b,
                                                  int nx, int n0c, int n2c) {
    int b = blockIdx.x;
    if (b < NBh) {
        int e = b * 256 + threadIdx.x;
        int ET = E + Nn;
        if (e >= ET) return;
        int d = (e < E) ? ei[E + e] : (e - E);
        atomicAdd(&deg[d], 1);
    } else {
        int i = ((b - NBh) * 256 + threadIdx.x) * 4;
        const float* in; u16* out;
        if (i < nx)            { in = x;  out = xb; }
        else if (i < nx + n0c) { in = W0; out = W0b; i -= nx; }
        else if (i < nx + n0c + n2c) { in = W2; out = W2b; i -= nx + n0c; }
        else return;
        float4 v = *reinterpret_cast<const float4*>(in + i);
        ushort4 o;
        o.x = f2bf(v.x); o.y = f2bf(v.y); o.z = f2bf(v.z); o.w = f2bf(v.w);
        *reinterpret_cast<ushort4*>(out + i) = o;
    }
}

// ---------------- scanA: per-1024-chunk inclusive scan + degree histogram ----------------

__global__ __launch_bounds__(1024) void scanA_k(const int* __restrict__ deg, int* __restrict__ incl,
                                                int* __restrict__ bsum, int* __restrict__ dbin, int n) {
    __shared__ int wsum[16];
    __shared__ int dh[256];
    int t = threadIdx.x;
    if (t < 256) dh[t] = 0;
    int i = blockIdx.x * 1024 + t;
    int v = (i < n) ? deg[i] : 0;
    __syncthreads();
    if (i < n) atomicAdd(&dh[v < 255 ? v : 255], 1);
    int lane = t & 63, wid = t >> 6;
    int sv = v;
    for (int off = 1; off < 64; off <<= 1) {
        int u = __shfl_up(sv, off, 64);
        if (lane >= off) sv += u;
    }
    if (lane == 63) wsum[wid] = sv;
    __syncthreads();
    if (t < 16) {
        int w = wsum[t];
        for (int off = 1; off < 16; off <<= 1) {
            int u = __shfl_up(w, off, 64);
            if (t >= off) w += u;
        }
        wsum[t] = w;
    }
    if (t < 256 && dh[t] > 0) atomicAdd(&dbin[t], dh[t]);
    __syncthreads();
    int pre = (wid > 0) ? wsum[wid - 1] : 0;
    int inc = pre + sv;
    if (i < n) incl[i] = inc;
    if (t == 1023) bsum[blockIdx.x] = inc;
}

// ---------------- scanBC: rowstart (each block re-scans <=64 chunk sums) ----------------

__global__ __launch_bounds__(256) void scanBC_k(const int* __restrict__ incl, const int* __restrict__ deg,
                                                const int* __restrict__ bsum, int* __restrict__ rowstart,
                                                int n, int B) {
    __shared__ int sb[65];
    int t = threadIdx.x;
    if (t < 64) {
        int v = (t < B) ? bsum[t] : 0;
        int sv = v;
        for (int off = 1; off < 64; off <<= 1) {
            int u = __shfl_up(sv, off, 64);
            if (t >= off) sv += u;
        }
        sb[t] = sv - v;
        if (t == 63) sb[64] = sv;
    }
    __syncthreads();
    int i = blockIdx.x * 256 + t;
    if (i < n) rowstart[i] = sb[i >> 10] + incl[i] - deg[i];
    if (i == 0) rowstart[n] = sb[64];
}

// ---------------- scatter: edges -> CSR srcs; node degree-sort (block-aggregated, DESC) ----------------

__global__ __launch_bounds__(256) void scatter_k(const int* __restrict__ ei,
                                                 const int* __restrict__ rowstart,
                                                 int* __restrict__ cursor,
                                                 int* __restrict__ srcs, int E, int Nn,
                                                 const int* __restrict__ deg,
                                                 const int* __restrict__ dbin,
                                                 int* __restrict__ dcur,
                                                 int* __restrict__ order) {
    int b = blockIdx.x, t = threadIdx.x;
    int e = b * 256 + t;
    int ET = E + Nn;
    if (e < ET) {
        int s, d;
        if (e < E) { s = ei[e]; d = ei[E + e]; }
        else       { s = e - E; d = e - E; }
        int pos = atomicAdd(&cursor[d], 1);
        srcs[rowstart[d] + pos] = s;
    }
    if (b * 256 < Nn) {
        __shared__ int ws4[4];
        __shared__ int sbase[256];
        __shared__ int lhist[256];
        __shared__ int lbase[256];
        lhist[t] = 0;
        int v = dbin[t];
        int lane = t & 63, wid = t >> 6;
        int sv = v;
        for (int off = 1; off < 64; off <<= 1) {
            int u = __shfl_up(sv, off, 64);
            if (lane >= off) sv += u;
        }
        if (lane == 63) ws4[wid] = sv;
        __syncthreads();
        int add = 0;
        for (int k = 0; k < wid; k++) add += ws4[k];
        sbase[t] = add + sv - v;
        __syncthreads();
        int i = b * 256 + t;
        int d = 0, rank = -1;
        if (i < Nn) {
            d = deg[i]; d = (d < 255) ? d : 255;
            rank = atomicAdd(&lhist[d], 1);
        }
        __syncthreads();
        int cnt = lhist[t];
        if (cnt > 0) lbase[t] = atomicAdd(&dcur[t], cnt);
        __syncthreads();
        if (i < Nn) order[Nn - 1 - (sbase[d] + lbase[d] + rank)] = i;
    }
}

// ---------------- bf16 MFMA GEMM -> fp8 C ----------------
// 128x64 tile, 4 waves; wave = 32 rows x 64 cols. B slab staged once; A
// streamed with a 4-deep register pipeline (8 loads in flight per wave).
// XCD swizzle: all col-blocks of a row-slab share lid%8 -> same XCD,
// consecutive -> A slice stays in that XCD's L2.

template<int KK>
__global__ __launch_bounds__(256, 4) void gemm_mfma(const u16* __restrict__ Ab,
                                                    const u16* __restrict__ Bb,
                                                    u8* __restrict__ Cf, int M, int Nc,
                                                    const float* __restrict__ avs_vec,
                                                    const float* __restrict__ avd_vec,
                                                    float* as_out, float* ad_out) {
    constexpr int SB = KK + 8;
    constexpr int BBY = 64 * SB * 2;
    constexpr int LBY = (BBY > 10240) ? BBY : 10240;
    __shared__ __align__(16) u8 lds[LBY];
    u16* Bs = reinterpret_cast<u16*>(lds);
    const int t = threadIdx.x;

    // XCD-aware swizzle: row = rowgrp*8 + (lid&7), col = (lid>>3) % GY
    const int lid = blockIdx.y * gridDim.x + blockIdx.x;
    const int GY = gridDim.y;
    const int r8 = lid & 7;
    const int rest = lid >> 3;
    const int row_blk = (rest / GY) * 8 + r8;
    const int col_blk = rest % GY;
    const int m0 = row_blk * 128;
    const int n0 = col_blk * 64;
    if (m0 >= M) return;   // padded row slabs (uniform across block, before any barrier)

    const int w = t >> 6, lane = t & 63;
    const int wr = w * 32;
    const int q = lane >> 4, l16 = lane & 15;

    constexpr int NKC = KK / 32;
    constexpr int PF = (NKC < 4) ? NKC : 4;

    const u16* A0 = Ab + (size_t)(m0 + wr + l16) * KK + q * 8;
    const u16* A1 = A0 + (size_t)16 * KK;
    v8s pa0[PF], pa1[PF];
#pragma unroll
    for (int k = 0; k < PF; k++) {
        pa0[k] = *reinterpret_cast<const v8s*>(A0 + k * 32);
        pa1[k] = *reinterpret_cast<const v8s*>(A1 + k * 32);
    }

    // stage whole B slab (64 rows x KK) once
    constexpr int CH = KK / 8;
#pragma unroll
    for (int c = t; c < 64 * CH; c += 256) {
        int row = c / CH, ch = c % CH;
        int gn = n0 + row;
        uint4 vb = make_uint4(0u, 0u, 0u, 0u);
        if (gn < Nc) vb = *reinterpret_cast<const uint4*>(Bb + (size_t)gn * KK + ch * 8);
        *reinterpret_cast<uint4*>(&Bs[row * SB + ch * 8]) = vb;
    }
    __syncthreads();

    v4f acc[2][4];
#pragma unroll
    for (int i = 0; i < 2; i++)
#pragma unroll
        for (int j = 0; j < 4; j++) acc[i][j] = (v4f){0.f, 0.f, 0.f, 0.f};

#pragma unroll
    for (int kc = 0; kc < NKC; kc++) {
        v8s a0 = pa0[kc % PF];
        v8s a1 = pa1[kc % PF];
        if (kc + PF < NKC) {
            pa0[kc % PF] = *reinterpret_cast<const v8s*>(A0 + (kc + PF) * 32);
            pa1[kc % PF] = *reinterpret_cast<const v8s*>(A1 + (kc + PF) * 32);
        }
        v8s bf[4];
#pragma unroll
        for (int j = 0; j < 4; j++)
            bf[j] = *reinterpret_cast<const v8s*>(&Bs[(j * 16 + l16) * SB + kc * 32 + q * 8]);
#pragma unroll
        for (int j = 0; j < 4; j++) {
            acc[0][j] = __builtin_amdgcn_mfma_f32_16x16x32_bf16(a0, bf[j], acc[0][j], 0, 0, 0);
            acc[1][j] = __builtin_amdgcn_mfma_f32_16x16x32_bf16(a1, bf[j], acc[1][j], 0, 0, 0);
        }
    }

    const bool do_att = (as_out != nullptr);
    float avs[4], avd[4];
    if (do_att) {
#pragma unroll
        for (int j = 0; j < 4; j++) {
            avs[j] = avs_vec[n0 + j * 16 + l16];
            avd[j] = avd_vec[n0 + j * 16 + l16];
        }
    }
    const int head = n0 >> 6;

    __syncthreads();   // B reads done; reuse lds for C repack
    u8* Cs = lds;
#pragma unroll
    for (int i = 0; i < 2; i++) {
#pragma unroll
        for (int r = 0; r < 4; r++) {
            int row = wr + i * 16 + q * 4 + r;
#pragma unroll
            for (int j = 0; j < 4; j++)
                Cs[row * 80 + j * 16 + l16] = enc8(acc[i][j][r]);
            if (do_att) {
                int gm = m0 + row;
                float ps = 0.f, pd = 0.f;
#pragma unroll
                for (int j = 0; j < 4; j++) {
                    float v = acc[i][j][r];
                    ps = fmaf(v, avs[j], ps);
                    pd = fmaf(v, avd[j], pd);
                }
#pragma unroll
                for (int m = 1; m < 16; m <<= 1) {
                    ps += __shfl_xor(ps, m, 64);
                    pd += __shfl_xor(pd, m, 64);
                }
                if (l16 == 0 && gm < M) {
                    as_out[gm * 8 + head] = ps;
                    ad_out[gm * 8 + head] = pd;
                }
            }
        }
    }
    __syncthreads();
#pragma unroll
    for (int it = 0; it < 2; it++) {
        int idx = it * 256 + t;
        int row = idx >> 2, ch = idx & 3;
        int gm = m0 + row;
        if (gm < M)
            *reinterpret_cast<uint4*>(Cf + (size_t)gm * Nc + n0 + ch * 16) =
                *reinterpret_cast<const uint4*>(&Cs[row * 80 + ch * 16]);
    }
}

// ---------------- layer-1 aggregation: wave/dst (degree-sorted), fp8 gather ----------------

__global__ __launch_bounds__(256) void agg1_k(const u8* __restrict__ h1f,
                                              const float* __restrict__ as1, const float* __restrict__ ad1,
                                              const int* __restrict__ srcs, const int* __restrict__ rowstart,
                                              const int* __restrict__ order,
                                              const float* __restrict__ b0, u16* __restrict__ x1b, int Nn) {
    int wave = threadIdx.x >> 6, lane = threadIdx.x & 63;
    int gid = blockIdx.x * 4 + wave;
    if (gid >= Nn) return;
    int n = __builtin_amdgcn_readfirstlane(order[gid]);
    const int hl = lane >> 3;
    const float adl = ad1[n * 8 + hl];
    const u32 loff = (u32)lane * 8u;
    float acc[8] = {0, 0, 0, 0, 0, 0, 0, 0};
    float dsum = 0.f;
    int beg = rowstart[n], end = rowstart[n + 1];
    int i = beg;
    for (; i + 8 <= end; i += 8) {
        int s[8];
#pragma unroll
        for (int u = 0; u < 8; u++) s[u] = __builtin_amdgcn_readfirstlane(srcs[i + u]);
        uint2 rw[8];
#pragma unroll
        for (int u = 0; u < 8; u++) rw[u] = *reinterpret_cast<const uint2*>(h1f + ((u32)s[u] * 512u + loff));
        float eg[8];
#pragma unroll
        for (int u = 0; u < 8; u++) eg[u] = as1[(u32)s[u] * 8u + hl];
        float p[8];
#pragma unroll
        for (int u = 0; u < 8; u++) { p[u] = lrelu_exp(eg[u] + adl); dsum += p[u]; }
#pragma unroll
        for (int u = 0; u < 8; u++) {
            float hv[8];
            dec8(rw[u], hv);
#pragma unroll
            for (int j = 0; j < 8; j++) acc[j] = fmaf(p[u], hv[j], acc[j]);
        }
    }
    for (; i + 4 <= end; i += 4) {
        int s[4];
#pragma unroll
        for (int u = 0; u < 4; u++) s[u] = __builtin_amdgcn_readfirstlane(srcs[i + u]);
        uint2 rw[4];
#pragma unroll
        for (int u = 0; u < 4; u++) rw[u] = *reinterpret_cast<const uint2*>(h1f + ((u32)s[u] * 512u + loff));
        float eg[4];
#pragma unroll
        for (int u = 0; u < 4; u++) eg[u] = as1[(u32)s[u] * 8u + hl];
#pragma unroll
        for (int u = 0; u < 4; u++) {
            float p = lrelu_exp(eg[u] + adl);
            dsum += p;
            float hv[8];
            dec8(rw[u], hv);
#pragma unroll
            for (int j = 0; j < 8; j++) acc[j] = fmaf(p, hv[j], acc[j]);
        }
    }
    for (; i < end; i++) {
        int s = __builtin_amdgcn_readfirstlane(srcs[i]);
        uint2 raw = *reinterpret_cast<const uint2*>(h1f + ((u32)s * 512u + loff));
        float p = lrelu_exp(as1[(u32)s * 8u + hl] + adl);
        dsum += p;
        float hv[8];
        dec8(raw, hv);
#pragma unroll
        for (int j = 0; j < 8; j++) acc[j] = fmaf(p, hv[j], acc[j]);
    }
    float inv = 1.f / (dsum + 1e-16f);
    float r[8];
#pragma unroll
    for (int j = 0; j < 8; j++) r[j] = acc[j] * inv;
#pragma unroll
    for (int j = 0; j < 8; j++) {
        r[j] += __shfl_xor(r[j], 8, 64);
        r[j] += __shfl_xor(r[j], 16, 64);
        r[j] += __shfl_xor(r[j], 32, 64);
    }
    if (lane < 8) {
        u16 o[8];
#pragma unroll
        for (int j = 0; j < 8; j++) {
            float v = r[j] * 0.125f + b0[lane * 8 + j];
            o[j] = f2bf((v > 0.f) ? v : 0.f);
        }
        *reinterpret_cast<uint4*>(x1b + (size_t)n * 64 + lane * 8) =
            *reinterpret_cast<const uint4*>(o);
    }
}

// ---------------- layer-2 attention logits ----------------

__global__ __launch_bounds__(256) void att2_k(const u8* __restrict__ h2f,
                                              const float* __restrict__ a2s, const float* __restrict__ a2d,
                                              float* __restrict__ as2, float* __restrict__ ad2, int Nn) {
    int t = blockIdx.x * 256 + threadIdx.x;
    if (t >= Nn * 8) return;
    int n = t >> 3, h = t & 7;
    const u8* hr = h2f + (size_t)n * 320 + h * 40;
    float s1 = 0.f, s2 = 0.f;
#pragma unroll
    for (int b = 0; b < 5; b++) {
        uint2 raw = *reinterpret_cast<const uint2*>(hr + b * 8);
        float h8[8];
        dec8(raw, h8);
#pragma unroll
        for (int j = 0; j < 8; j++) {
            int c = h * 40 + b * 8 + j;
            s1 = fmaf(h8[j], a2s[c], s1);
            s2 = fmaf(h8[j], a2d[c], s2);
        }
    }
    as2[t] = s1;
    ad2[t] = s2;
}

// ---------------- layer-2 aggregation (degree-sorted) + head-mean + log_softmax ----------------

__global__ __launch_bounds__(256) void agg2_k(const u8* __restrict__ h2f,
                                              const float* __restrict__ as2, const float* __restrict__ ad2,
                                              const int* __restrict__ srcs, const int* __restrict__ rowstart,
                                              const int* __restrict__ order,
                                              const float* __restrict__ b2, float* __restrict__ out, int Nn) {
    __shared__ float smem[4][320];
    int wave = threadIdx.x >> 6, lane = threadIdx.x & 63;
    int gid = blockIdx.x * 4 + wave;
    bool active = (gid < Nn);
    int n = 0;
    if (active) n = __builtin_amdgcn_readfirstlane(order[gid]);
    bool ld = active && (lane < 40);
    const int hl = lane / 5;
    float adl = ld ? ad2[n * 8 + hl] : 0.f;
    float acc[8] = {0, 0, 0, 0, 0, 0, 0, 0};
    float dsum = 0.f;
    if (ld) {
        const u32 loff = (u32)lane * 8u;
        int beg = rowstart[n], end = rowstart[n + 1];
        int i = beg;
        for (; i + 8 <= end; i += 8) {
            int s[8];
#pragma unroll
            for (int u = 0; u < 8; u++) s[u] = __builtin_amdgcn_readfirstlane(srcs[i + u]);
            uint2 rw[8];
#pragma unroll
            for (int u = 0; u < 8; u++) rw[u] = *reinterpret_cast<const uint2*>(h2f + ((u32)s[u] * 320u + loff));
            float eg[8];
#pragma unroll
            for (int u = 0; u < 8; u++) eg[u] = as2[(u32)s[u] * 8u + hl];
            float p[8];
#pragma unroll
            for (int u = 0; u < 8; u++) { p[u] = lrelu_exp(eg[u] + adl); dsum += p[u]; }
#pragma unroll
            for (int u = 0; u < 8; u++) {
                float hv[8];
                dec8(rw[u], hv);
#pragma unroll
                for (int j = 0; j < 8; j++) acc[j] = fmaf(p[u], hv[j], acc[j]);
            }
        }
        for (; i + 4 <= end; i += 4) {
            int s[4];
#pragma unroll
            for (int u = 0; u < 4; u++) s[u] = __builtin_amdgcn_readfirstlane(srcs[i + u]);
            uint2 rw[4];
#pragma unroll
            for (int u = 0; u < 4; u++) rw[u] = *reinterpret_cast<const uint2*>(h2f + ((u32)s[u] * 320u + loff));
            float eg[4];
#pragma unroll
            for (int u = 0; u < 4; u++) eg[u] = as2[(u32)s[u] * 8u + hl];
#pragma unroll
            for (int u = 0; u < 4; u++) {
                float p = lrelu_exp(eg[u] + adl);
                dsum += p;
                float hv[8];
                dec8(rw[u], hv);
#pragma unroll
                for (int j = 0; j < 8; j++) acc[j] = fmaf(p, hv[j], acc[j]);
            }
        }
        for (; i < end; i++) {
            int s = __builtin_amdgcn_readfirstlane(srcs[i]);
            uint2 raw = *reinterpret_cast<const uint2*>(h2f + ((u32)s * 320u + loff));
            float p = lrelu_exp(as2[(u32)s * 8u + hl] + adl);
            dsum += p;
            float hv[8];
            dec8(raw, hv);
#pragma unroll
            for (int j = 0; j < 8; j++) acc[j] = fmaf(p, hv[j], acc[j]);
        }
        float inv = 1.f / (dsum + 1e-16f);
#pragma unroll
        for (int j = 0; j < 8; j++) smem[wave][lane * 8 + j] = acc[j] * inv;
    }
    __syncthreads();
    if (active) {
        float v;
        if (lane < 40) {
            float ssum = 0.f;
#pragma unroll
            for (int h = 0; h < 8; h++) ssum += smem[wave][h * 40 + lane];
            v = ssum * 0.125f + b2[lane];
        } else {
            v = -INFINITY;
        }
        float m = v;
        for (int off = 32; off > 0; off >>= 1) m = fmaxf(m, __shfl_xor(m, off, 64));
        float ex = (lane < 40) ? __expf(v - m) : 0.f;
        float se = ex;
        for (int off = 32; off > 0; off >>= 1) se += __shfl_xor(se, off, 64);
        if (lane < 40) out[(size_t)n * 40 + lane] = v - m - __logf(se);
    }
}

// ---------------- launch ----------------

extern "C" void kernel_launch(void* const* d_in, const int* in_sizes, int n_in,
                              void* d_out, int out_size, void* d_ws, size_t ws_size,
                              hipStream_t stream) {
    const float* x   = (const float*)d_in[0];
    const int*   ei  = (const int*)d_in[1];
    const float* W0  = (const float*)d_in[3];
    const float* a0s = (const float*)d_in[4];
    const float* a0d = (const float*)d_in[5];
    const float* b0  = (const float*)d_in[6];
    const float* W2  = (const float*)d_in[7];
    const float* a2s = (const float*)d_in[8];
    const float* a2d = (const float*)d_in[9];
    const float* b2  = (const float*)d_in[10];
    float* out = (float*)d_out;

    const int Nn = in_sizes[0] / 256;   // 50000
    const int E  = in_sizes[1] / 2;     // 800000
    const int ET = E + Nn;
    const int NB = (Nn + 1023) / 1024;  // scan chunks (<=64)

    size_t off = 0;
    auto carve = [&](size_t bytes) -> void* {
        void* p = (char*)d_ws + off;
        off += (bytes + 255) & ~(size_t)255;
        return p;
    };
    u16*   xb       = (u16*)carve((size_t)Nn * 256 * 2);
    u16*   W0b      = (u16*)carve((size_t)512 * 256 * 2);
    u16*   W2b      = (u16*)carve((size_t)320 * 64 * 2);
    u8*    h1f      = (u8*)carve((size_t)Nn * 512);
    u16*   x1b      = (u16*)carve((size_t)Nn * 64 * 2);
    u8*    h2f      = (u8*)carve((size_t)Nn * 320);
    float* as1      = (float*)carve((size_t)Nn * 8 * 4);
    float* ad1      = (float*)carve((size_t)Nn * 8 * 4);
    float* as2      = (float*)carve((size_t)Nn * 8 * 4);
    float* ad2      = (float*)carve((size_t)Nn * 8 * 4);
    // zeroed region: deg, cursor, dbin, dcur (contiguous, one memset)
    int*   deg      = (int*)carve((size_t)Nn * 4);
    int*   cursor   = (int*)carve((size_t)Nn * 4);
    int*   dbin     = (int*)carve(256 * 4);
    int*   dcur     = (int*)carve(256 * 4);
    int*   rowstart = (int*)carve((size_t)(Nn + 1) * 4);
    int*   srcs     = (int*)carve((size_t)ET * 4);
    int*   incl     = (int*)carve((size_t)Nn * 4);
    int*   bsum     = (int*)carve(64 * 4);
    int*   order    = (int*)carve((size_t)Nn * 4);

    const size_t zlen = (size_t)((char*)rowstart - (char*)deg);
    hipMemsetAsync(deg, 0, zlen, stream);   // deg+cursor+dbin+dcur

    const int nx = Nn * 256, n0c = 512 * 256, n2c = 320 * 64;
    const int NBh = (ET + 255) / 256;
    const int NBc = ((nx + n0c + n2c) / 4 + 255) / 256;
    histcast_k<<<NBh + NBc, 256, 0, stream>>>(ei, deg, E, Nn, NBh,
                                              x, xb, W0, W0b, W2, W2b, nx, n0c, n2c);
    scanA_k<<<NB, 1024, 0, stream>>>(deg, incl, bsum, dbin, Nn);
    scanBC_k<<<(Nn + 255) / 256, 256, 0, stream>>>(incl, deg, bsum, rowstart, Nn, NB);
    scatter_k<<<(ET + 255) / 256, 256, 0, stream>>>(ei, rowstart, cursor, srcs, E, Nn,
                                                    deg, dbin, dcur, order);

    // row slabs padded to a multiple of 8 for the XCD swizzle
    const int GXr = (Nn + 127) / 128;            // 391 real row slabs
    const int GX  = ((GXr + 7) / 8) * 8;         // 392 padded

    // layer 1: GEMM + fused logits, fp8 h1
    gemm_mfma<256><<<dim3(GX, 8), 256, 0, stream>>>(
        xb, W0b, h1f, Nn, 512, a0s, a0d, as1, ad1);
    agg1_k<<<(Nn + 3) / 4, 256, 0, stream>>>(h1f, as1, ad1, srcs, rowstart, order, b0, x1b, Nn);

    // layer 2: GEMM, fp8 h2
    gemm_mfma<64><<<dim3(GX, 5), 256, 0, stream>>>(
        x1b, W2b, h2f, Nn, 320, nullptr, nullptr, nullptr, nullptr);
    att2_k<<<(Nn * 8 + 255) / 256, 256, 0, stream>>>(h2f, a2s, a2d, as2, ad2, Nn);
    agg2_k<<<(Nn + 3) / 4, 256, 0, stream>>>(h2f, as2, ad2, srcs, rowstart, order, b2, out, Nn);
}